// Round 4
// baseline (537.234 us; speedup 1.0000x reference)
//
#include <hip/hip_runtime.h>

typedef __attribute__((ext_vector_type(2))) float f32x2;
typedef __attribute__((ext_vector_type(4))) float f32x4;
typedef __attribute__((ext_vector_type(8))) short bf16x8;
typedef __attribute__((ext_vector_type(2))) unsigned u32x2;

#define MFMA16(a, b, c) __builtin_amdgcn_mfma_f32_16x16x32_bf16(a, b, c, 0, 0, 0)

// ws fragment offsets in shorts (bf16 elements)
#define W1F_OFF 0        // 16384 elems (M=256,K=64,  KT=2)
#define W2F_OFF 16384    // 65536 elems (M=256,K=256, KT=8)
#define CF_OFF  81920    // 65536 elems (M=256,K=256, KT=8)
#define W3F_OFF 147456   // 16384 elems (M=64, K=256, KT=8)

__device__ __forceinline__ short f2bf(float f) {
  unsigned u = __builtin_bit_cast(unsigned, f);
  u += 0x7FFFu + ((u >> 16) & 1u);          // RTNE (finite values only)
  return (short)(u >> 16);
}

__device__ __forceinline__ unsigned cvt_pk_bf16(float lo, float hi) {
  unsigned r;
  asm("v_cvt_pk_bf16_f32 %0, %1, %2" : "=v"(r) : "v"(lo), "v"(hi));
  return r;
}

__device__ __forceinline__ void sp_sig(float z, float& h, float& s) {
  // softplus + sigmoid sharing one exp: t = 2^(-|z|*log2e)
  float a = fabsf(z);
#if __has_builtin(__builtin_amdgcn_exp2f)
  float t = __builtin_amdgcn_exp2f(a * -1.44269504f);
#else
  float t = __expf(-a);
#endif
  float o = 1.f + t;
#if __has_builtin(__builtin_amdgcn_rcpf)
  float r = __builtin_amdgcn_rcpf(o);
#else
  float r = 1.f / o;
#endif
#if __has_builtin(__builtin_amdgcn_logf)
  float l2 = __builtin_amdgcn_logf(o);          // log2(o)
#else
  float l2 = __logf(o) * 1.44269504f;
#endif
  h = fmaxf(z, 0.f) + 0.69314718f * l2;
  s = (z >= 0.f) ? r : 1.f - r;
}

// softplus+sigmoid over an f32x4, packed outputs
__device__ __forceinline__ void sp_sig4(const f32x4& z, u32x2& hp, f32x4& sv) {
  float h0, h1, h2, h3, s0, s1, s2, s3;
  sp_sig(z[0], h0, s0); sp_sig(z[1], h1, s1);
  sp_sig(z[2], h2, s2); sp_sig(z[3], h3, s3);
  hp[0] = cvt_pk_bf16(h0, h1); hp[1] = cvt_pk_bf16(h2, h3);
  sv[0] = s0; sv[1] = s1; sv[2] = s2; sv[3] = s3;
}

// ---------------------------------------------------------------------------
// Prep: swizzle W1, W2, C = W2 .* (W1@W3)^T, W3 into MFMA A-fragment order.
// A[m][k] with m = mt*16 + (lane&15), k = kt*32 + (lane>>4)*8 + j
// ---------------------------------------------------------------------------
__global__ __launch_bounds__(512) void cnf_prep(const float* __restrict__ W1,
                                                const float* __restrict__ W2,
                                                const float* __restrict__ W3,
                                                short* __restrict__ ws) {
  int e = blockIdx.x * 512 + threadIdx.x;   // [0, 163840)
  int j = e & 7;
  int l = (e >> 3) & 63;
  int g = l >> 4, lm = l & 15;
  float val;
  if (e < 16384) {                          // W1 frag: [256 x 64]
    int t = e >> 9, kt = t & 1, mt = t >> 1;
    val = W1[(mt * 16 + lm) * 64 + kt * 32 + g * 8 + j];
  } else if (e < 81920) {                   // W2 frag: [256 x 256]
    int t = (e - 16384) >> 9, kt = t & 7, mt = t >> 3;
    val = W2[(mt * 16 + lm) * 256 + kt * 32 + g * 8 + j];
  } else if (e < 147456) {                  // C frag: C[m][k] = W2[m,k]*A2[k,m]
    int t = (e - 81920) >> 9, kt = t & 7, mt = t >> 3;
    int m = mt * 16 + lm, k = kt * 32 + g * 8 + j;
    float a2 = 0.f;
#pragma unroll 16
    for (int d = 0; d < 64; ++d) a2 += W1[k * 64 + d] * W3[d * 256 + m];
    val = W2[m * 256 + k] * a2;
  } else {                                  // W3 frag: [64 x 256]
    int t = (e - 147456) >> 9, kt = t & 7, mt = t >> 3;
    val = W3[(mt * 16 + lm) * 256 + kt * 32 + g * 8 + j];
  }
  ws[e] = f2bf(val);
}

// ---------------------------------------------------------------------------
// Main: 256 blocks x 1024 threads (16 waves, 4/SIMD, 128 VGPR budget).
// Block b integrates samples [32b, 32b+32) through 10 Dopri5 steps.
// Per dyn(): 4 bf16 MFMA GEMMs. Wave wv owns M-tile mt=wv (GEMM1/2/C, M=256)
// x 2 col tiles (N=32). GEMM3 (M=64): wave -> (mt=wv&3, col=(wv>>2)&1,
// khalf=wv>>3), partial-sum LDS. Biases folded into MFMA acc init.
// ---------------------------------------------------------------------------
__global__ __launch_bounds__(1024, 4) void cnf_main(
    const float* __restrict__ x, const float* __restrict__ ld_init,
    const float* __restrict__ b1g, const float* __restrict__ b2g,
    const float* __restrict__ b3g, const float* __restrict__ Tg,
    const short* __restrict__ ws, float* __restrict__ outy,
    float* __restrict__ outl) {
  __shared__ __align__(16) short w1f[16384];       // 32 KB persistent W1 frags
  __shared__ __align__(16) short w3f[16384];       // 32 KB persistent W3 frags
  __shared__ __align__(16) short ytL[32 * 88];     // stage input bf16 [s][d]
  __shared__ __align__(16) short h1L[32 * 264];    // softplus(z1) [col][row]
  __shared__ __align__(16) short s1L_[32 * 264];   // sigmoid(z1)
  __shared__ __align__(16) short h2L[32 * 264];    // softplus(z2)
  __shared__ __align__(16) float dyL[2][32][68];   // K-split partial dy
  __shared__ __align__(16) float trPT[32][16];     // trace partials [s][wv]

  const int tid = threadIdx.x;
  const int lane = tid & 63, wv = tid >> 6;        // 16 waves
  const int sl = tid >> 5, q2 = tid & 31;          // sample-local, dim-pair
  const int lg = lane >> 4, lm = lane & 15;
  const int ko8 = lg << 3;

  // Stage persistent weight fragments into LDS (2 x 16B per thread each)
  {
    const f32x4* s1p = (const f32x4*)(ws + W1F_OFF);
    f32x4* d1 = (f32x4*)w1f;
    d1[tid] = s1p[tid]; d1[tid + 1024] = s1p[tid + 1024];
    const f32x4* s3p = (const f32x4*)(ws + W3F_OFF);
    f32x4* d3 = (f32x4*)w3f;
    d3[tid] = s3p[tid]; d3[tid + 1024] = s3p[tid + 1024];
  }

  const int row0 = wv * 16 + (lg << 2);
  const f32x4 bias1 = *(const f32x4*)&b1g[row0];
  const f32x4 bias2 = *(const f32x4*)&b2g[row0];
  const int m3 = wv & 3, c3 = (wv >> 2) & 1, kh = wv >> 3;
  f32x4 bias3 = {0.f, 0.f, 0.f, 0.f};
  if (kh == 0) bias3 = *(const f32x4*)&b3g[m3 * 16 + (lg << 2)];

  const bf16x8* w2fG = (const bf16x8*)(ws + W2F_OFF);
  const bf16x8* cfG  = (const bf16x8*)(ws + CF_OFF);

  const int sg = blockIdx.x * 32 + sl;
  f32x2 y = *(const f32x2*)&x[sg * 64 + q2 * 2];
  float ld = ld_init[sg];
  const float dt = Tg[0] * 0.1f;                   // T / NUM_STEPS

  __syncthreads();

  auto dyn = [&](f32x2 yin, f32x2& dy, float& tr) {
    *(unsigned*)&ytL[sl * 88 + q2 * 2] = cvt_pk_bf16(yin[0], yin[1]);
    __syncthreads();                               // B1: ytmp ready

    // ---- GEMM1: z1^T = W1 * ytmp^T  (K=64), acc init = b1
    f32x4 a0 = bias1, a1 = bias1;
#pragma unroll
    for (int kt = 0; kt < 2; ++kt) {
      bf16x8 A = *(const bf16x8*)&w1f[((wv * 2 + kt) * 64 + lane) * 8];
      bf16x8 B0 = *(const bf16x8*)&ytL[lm * 88 + kt * 32 + ko8];
      bf16x8 B1 = *(const bf16x8*)&ytL[(16 + lm) * 88 + kt * 32 + ko8];
      a0 = MFMA16(A, B0, a0); a1 = MFMA16(A, B1, a1);
    }
    {
      u32x2 hp; f32x4 sv;
      sp_sig4(a0, hp, sv);
      u32x2 sp0 = {cvt_pk_bf16(sv[0], sv[1]), cvt_pk_bf16(sv[2], sv[3])};
      *(u32x2*)&h1L[lm * 264 + row0] = hp;
      *(u32x2*)&s1L_[lm * 264 + row0] = sp0;
      sp_sig4(a1, hp, sv);
      u32x2 sp1 = {cvt_pk_bf16(sv[0], sv[1]), cvt_pk_bf16(sv[2], sv[3])};
      *(u32x2*)&h1L[(16 + lm) * 264 + row0] = hp;
      *(u32x2*)&s1L_[(16 + lm) * 264 + row0] = sp1;
    }
    __syncthreads();                               // B2: h1, s1 ready

    // ---- GEMM2: z2^T = W2 * h1^T (K=256), acc init = b2
    f32x4 c0 = bias2, c1 = bias2;
#pragma unroll
    for (int kt = 0; kt < 8; ++kt) {
      bf16x8 A = w2fG[(wv * 8 + kt) * 64 + lane];
      bf16x8 B0 = *(const bf16x8*)&h1L[lm * 264 + kt * 32 + ko8];
      bf16x8 B1 = *(const bf16x8*)&h1L[(16 + lm) * 264 + kt * 32 + ko8];
      c0 = MFMA16(A, B0, c0); c1 = MFMA16(A, B1, c1);
    }
    f32x4 s20, s21;
    {
      u32x2 hp;
      sp_sig4(c0, hp, s20);
      *(u32x2*)&h2L[lm * 264 + row0] = hp;
      sp_sig4(c1, hp, s21);
      *(u32x2*)&h2L[(16 + lm) * 264 + row0] = hp;
    }

    // ---- GEMMC: u^T = C * s1^T (K=256) — s1 ready since B2, overlap epi2
    f32x4 u0 = {0.f, 0.f, 0.f, 0.f}, u1 = {0.f, 0.f, 0.f, 0.f};
#pragma unroll
    for (int kt = 0; kt < 8; ++kt) {
      bf16x8 A = cfG[(wv * 8 + kt) * 64 + lane];
      bf16x8 B0 = *(const bf16x8*)&s1L_[lm * 264 + kt * 32 + ko8];
      bf16x8 B1 = *(const bf16x8*)&s1L_[(16 + lm) * 264 + kt * 32 + ko8];
      u0 = MFMA16(A, B0, u0); u1 = MFMA16(A, B1, u1);
    }
    float pl0 = u0[0] * s20[0] + u0[1] * s20[1] + u0[2] * s20[2] + u0[3] * s20[3];
    float pl1 = u1[0] * s21[0] + u1[1] * s21[1] + u1[2] * s21[2] + u1[3] * s21[3];
    pl0 += __shfl_xor(pl0, 16); pl0 += __shfl_xor(pl0, 32);
    pl1 += __shfl_xor(pl1, 16); pl1 += __shfl_xor(pl1, 32);
    if (lane < 16) { trPT[lm][wv] = pl0; trPT[16 + lm][wv] = pl1; }
    __syncthreads();                               // B3: h2 ready

    // ---- GEMM3: dy^T = W3 * h2^T (K=256, 2-way K-split), acc init = b3/0
    f32x4 d3a = bias3;
#pragma unroll
    for (int k = 0; k < 4; ++k) {
      int kt = kh * 4 + k;
      bf16x8 A = *(const bf16x8*)&w3f[((m3 * 8 + kt) * 64 + lane) * 8];
      bf16x8 B = *(const bf16x8*)&h2L[(c3 * 16 + lm) * 264 + kt * 32 + ko8];
      d3a = MFMA16(A, B, d3a);
    }
    *(f32x4*)&dyL[kh][c3 * 16 + lm][m3 * 16 + (lg << 2)] = d3a;
    __syncthreads();                               // B4: dy, trace ready

    f32x2 da = *(const f32x2*)&dyL[0][sl][q2 * 2];
    f32x2 db = *(const f32x2*)&dyL[1][sl][q2 * 2];
    dy = da + db;
    f32x4 t0 = *(const f32x4*)&trPT[sl][0];
    f32x4 t1 = *(const f32x4*)&trPT[sl][4];
    f32x4 t2 = *(const f32x4*)&trPT[sl][8];
    f32x4 t3 = *(const f32x4*)&trPT[sl][12];
    f32x4 ts = t0 + t1 + t2 + t3;
    tr = ts[0] + ts[1] + ts[2] + ts[3];
  };

  // Dormand-Prince 5(4), fixed 10 steps; dt premultiplied into coefficients
  const float A21 = dt * (1.f / 5.f);
  const float A31 = dt * (3.f / 40.f), A32 = dt * (9.f / 40.f);
  const float A41 = dt * (44.f / 45.f), A42 = dt * (-56.f / 15.f),
              A43 = dt * (32.f / 9.f);
  const float A51 = dt * (19372.f / 6561.f), A52 = dt * (-25360.f / 2187.f),
              A53 = dt * (64448.f / 6561.f), A54 = dt * (-212.f / 729.f);
  const float A61 = dt * (9017.f / 3168.f), A62 = dt * (-355.f / 33.f),
              A63 = dt * (46732.f / 5247.f), A64 = dt * (49.f / 176.f),
              A65 = dt * (-5103.f / 18656.f);
  const float C1 = dt * (35.f / 384.f), C3 = dt * (500.f / 1113.f),
              C4 = dt * (125.f / 192.f), C5 = dt * (-2187.f / 6784.f),
              C6 = dt * (11.f / 84.f);

  f32x2 k1, k2, k3, k4, k5, k6;
  float l1, l2, l3, l4, l5, l6;
#pragma unroll 1
  for (int step = 0; step < 10; ++step) {
    dyn(y, k1, l1);
    dyn(y + A21 * k1, k2, l2);
    dyn(y + A31 * k1 + A32 * k2, k3, l3);
    dyn(y + A41 * k1 + A42 * k2 + A43 * k3, k4, l4);
    dyn(y + A51 * k1 + A52 * k2 + A53 * k3 + A54 * k4, k5, l5);
    dyn(y + A61 * k1 + A62 * k2 + A63 * k3 + A64 * k4 + A65 * k5, k6, l6);
    y = y + C1 * k1 + C3 * k3 + C4 * k4 + C5 * k5 + C6 * k6;
    ld = ld + C1 * l1 + C3 * l3 + C4 * l4 + C5 * l5 + C6 * l6;
  }

  *(f32x2*)&outy[sg * 64 + q2 * 2] = y;
  if (q2 == 0) outl[sg] = ld;
}

extern "C" void kernel_launch(void* const* d_in, const int* in_sizes, int n_in,
                              void* d_out, int out_size, void* d_ws, size_t ws_size,
                              hipStream_t stream) {
  const float* x  = (const float*)d_in[0];
  const float* l0 = (const float*)d_in[1];
  const float* W1 = (const float*)d_in[2];
  const float* b1 = (const float*)d_in[3];
  const float* W2 = (const float*)d_in[4];
  const float* b2 = (const float*)d_in[5];
  const float* W3 = (const float*)d_in[6];
  const float* b3 = (const float*)d_in[7];
  const float* Tp = (const float*)d_in[8];
  short* ws = (short*)d_ws;

  cnf_prep<<<dim3(320), dim3(512), 0, stream>>>(W1, W2, W3, ws);

  float* outy = (float*)d_out;
  float* outl = outy + 8192 * 64;
  cnf_main<<<dim3(256), dim3(1024), 0, stream>>>(x, l0, b1, b2, b3, Tp, ws,
                                                 outy, outl);
}

// Round 5
// 536.661 us; speedup vs baseline: 1.0011x; 1.0011x over previous
//
#include <hip/hip_runtime.h>

typedef __attribute__((ext_vector_type(2))) float f32x2;
typedef __attribute__((ext_vector_type(4))) float f32x4;
typedef __attribute__((ext_vector_type(8))) short bf16x8;
typedef __attribute__((ext_vector_type(2))) unsigned u32x2;

#define MFMA16(a, b, c) __builtin_amdgcn_mfma_f32_16x16x32_bf16(a, b, c, 0, 0, 0)

// ws fragment offsets in shorts (bf16 elements)
#define W1F_OFF 0        // 16384 elems (M=256,K=64,  KT=2)
#define W2F_OFF 16384    // 65536 elems (M=256,K=256, KT=8)
#define CF_OFF  81920    // 65536 elems (M=256,K=256, KT=8)
#define W3F_OFF 147456   // 16384 elems (M=64, K=256, KT=8)

__device__ __forceinline__ short f2bf(float f) {
  unsigned u = __builtin_bit_cast(unsigned, f);
  u += 0x7FFFu + ((u >> 16) & 1u);          // RTNE (finite values only)
  return (short)(u >> 16);
}

__device__ __forceinline__ unsigned cvt_pk_bf16(float lo, float hi) {
  unsigned r;
  asm("v_cvt_pk_bf16_f32 %0, %1, %2" : "=v"(r) : "v"(lo), "v"(hi));
  return r;
}

__device__ __forceinline__ void sp_sig(float z, float& h, float& s) {
  // softplus + sigmoid sharing one exp: t = 2^(-|z|*log2e)
  float a = fabsf(z);
#if __has_builtin(__builtin_amdgcn_exp2f)
  float t = __builtin_amdgcn_exp2f(a * -1.44269504f);
#else
  float t = __expf(-a);
#endif
  float o = 1.f + t;
#if __has_builtin(__builtin_amdgcn_rcpf)
  float r = __builtin_amdgcn_rcpf(o);
#else
  float r = 1.f / o;
#endif
#if __has_builtin(__builtin_amdgcn_logf)
  float l2 = __builtin_amdgcn_logf(o);          // log2(o)
#else
  float l2 = __logf(o) * 1.44269504f;
#endif
  h = fmaxf(z, 0.f) + 0.69314718f * l2;
  s = (z >= 0.f) ? r : 1.f - r;
}

// softplus+sigmoid over an f32x4, packed outputs
__device__ __forceinline__ void sp_sig4(const f32x4& z, u32x2& hp, f32x4& sv) {
  float h0, h1, h2, h3, s0, s1, s2, s3;
  sp_sig(z[0], h0, s0); sp_sig(z[1], h1, s1);
  sp_sig(z[2], h2, s2); sp_sig(z[3], h3, s3);
  hp[0] = cvt_pk_bf16(h0, h1); hp[1] = cvt_pk_bf16(h2, h3);
  sv[0] = s0; sv[1] = s1; sv[2] = s2; sv[3] = s3;
}

// ---------------------------------------------------------------------------
// Prep: swizzle W1, W2, C = W2 .* (W1@W3)^T, W3 into MFMA A-fragment order.
// A[m][k] with m = mt*16 + (lane&15), k = kt*32 + (lane>>4)*8 + j
// ---------------------------------------------------------------------------
__global__ __launch_bounds__(512) void cnf_prep(const float* __restrict__ W1,
                                                const float* __restrict__ W2,
                                                const float* __restrict__ W3,
                                                short* __restrict__ ws) {
  int e = blockIdx.x * 512 + threadIdx.x;   // [0, 163840)
  int j = e & 7;
  int l = (e >> 3) & 63;
  int g = l >> 4, lm = l & 15;
  float val;
  if (e < 16384) {                          // W1 frag: [256 x 64]
    int t = e >> 9, kt = t & 1, mt = t >> 1;
    val = W1[(mt * 16 + lm) * 64 + kt * 32 + g * 8 + j];
  } else if (e < 81920) {                   // W2 frag: [256 x 256]
    int t = (e - 16384) >> 9, kt = t & 7, mt = t >> 3;
    val = W2[(mt * 16 + lm) * 256 + kt * 32 + g * 8 + j];
  } else if (e < 147456) {                  // C frag: C[m][k] = W2[m,k]*A2[k,m]
    int t = (e - 81920) >> 9, kt = t & 7, mt = t >> 3;
    int m = mt * 16 + lm, k = kt * 32 + g * 8 + j;
    float a2 = 0.f;
#pragma unroll 16
    for (int d = 0; d < 64; ++d) a2 += W1[k * 64 + d] * W3[d * 256 + m];
    val = W2[m * 256 + k] * a2;
  } else {                                  // W3 frag: [64 x 256]
    int t = (e - 147456) >> 9, kt = t & 7, mt = t >> 3;
    val = W3[(mt * 16 + lm) * 256 + kt * 32 + g * 8 + j];
  }
  ws[e] = f2bf(val);
}

// ---------------------------------------------------------------------------
// Main: 256 blocks x 1024 threads (16 waves, 1 block/CU via LDS).
// amdgpu_waves_per_eu(4,4): pin the allocator's occupancy target to the
// LDS-imposed 4 waves/EU -> 128-VGPR budget, no scratch spill. (The
// __launch_bounds__ 2nd arg only sets the MIN and let the allocator target
// 8 waves/EU -> 64 VGPR -> 870 MB spill traffic in rounds 3/4.)
// ---------------------------------------------------------------------------
__global__ __launch_bounds__(1024)
__attribute__((amdgpu_waves_per_eu(4, 4))) void cnf_main(
    const float* __restrict__ x, const float* __restrict__ ld_init,
    const float* __restrict__ b1g, const float* __restrict__ b2g,
    const float* __restrict__ b3g, const float* __restrict__ Tg,
    const short* __restrict__ ws, float* __restrict__ outy,
    float* __restrict__ outl) {
  __shared__ __align__(16) short w1f[16384];       // 32 KB persistent W1 frags
  __shared__ __align__(16) short w3f[16384];       // 32 KB persistent W3 frags
  __shared__ __align__(16) short ytL[32 * 88];     // stage input bf16 [s][d]
  __shared__ __align__(16) short h1L[32 * 264];    // softplus(z1) [col][row]
  __shared__ __align__(16) short s1L_[32 * 264];   // sigmoid(z1)
  __shared__ __align__(16) short h2L[32 * 264];    // softplus(z2)
  __shared__ __align__(16) float dyL[2][32][68];   // K-split partial dy
  __shared__ __align__(16) float trPT[32][16];     // trace partials [s][wv]

  const int tid = threadIdx.x;
  const int lane = tid & 63, wv = tid >> 6;        // 16 waves
  const int sl = tid >> 5, q2 = tid & 31;          // sample-local, dim-pair
  const int lg = lane >> 4, lm = lane & 15;
  const int ko8 = lg << 3;

  // Stage persistent weight fragments into LDS (2 x 16B per thread each)
  {
    const f32x4* s1p = (const f32x4*)(ws + W1F_OFF);
    f32x4* d1 = (f32x4*)w1f;
    d1[tid] = s1p[tid]; d1[tid + 1024] = s1p[tid + 1024];
    const f32x4* s3p = (const f32x4*)(ws + W3F_OFF);
    f32x4* d3 = (f32x4*)w3f;
    d3[tid] = s3p[tid]; d3[tid + 1024] = s3p[tid + 1024];
  }

  const int row0 = wv * 16 + (lg << 2);
  const f32x4 bias1 = *(const f32x4*)&b1g[row0];
  const f32x4 bias2 = *(const f32x4*)&b2g[row0];
  const int m3 = wv & 3, c3 = (wv >> 2) & 1, kh = wv >> 3;
  f32x4 bias3 = {0.f, 0.f, 0.f, 0.f};
  if (kh == 0) bias3 = *(const f32x4*)&b3g[m3 * 16 + (lg << 2)];

  const bf16x8* w2fG = (const bf16x8*)(ws + W2F_OFF);
  const bf16x8* cfG  = (const bf16x8*)(ws + CF_OFF);

  const int sg = blockIdx.x * 32 + sl;
  f32x2 y = *(const f32x2*)&x[sg * 64 + q2 * 2];
  float ld = ld_init[sg];
  const float dt = Tg[0] * 0.1f;                   // T / NUM_STEPS

  __syncthreads();

  auto dyn = [&](f32x2 yin, f32x2& dy, float& tr) {
    *(unsigned*)&ytL[sl * 88 + q2 * 2] = cvt_pk_bf16(yin[0], yin[1]);
    __syncthreads();                               // B1: ytmp ready

    // ---- GEMM1: z1^T = W1 * ytmp^T  (K=64), acc init = b1
    f32x4 a0 = bias1, a1 = bias1;
#pragma unroll
    for (int kt = 0; kt < 2; ++kt) {
      bf16x8 A = *(const bf16x8*)&w1f[((wv * 2 + kt) * 64 + lane) * 8];
      bf16x8 B0 = *(const bf16x8*)&ytL[lm * 88 + kt * 32 + ko8];
      bf16x8 B1 = *(const bf16x8*)&ytL[(16 + lm) * 88 + kt * 32 + ko8];
      a0 = MFMA16(A, B0, a0); a1 = MFMA16(A, B1, a1);
    }
    {
      u32x2 hp; f32x4 sv;
      sp_sig4(a0, hp, sv);
      u32x2 sp0 = {cvt_pk_bf16(sv[0], sv[1]), cvt_pk_bf16(sv[2], sv[3])};
      *(u32x2*)&h1L[lm * 264 + row0] = hp;
      *(u32x2*)&s1L_[lm * 264 + row0] = sp0;
      sp_sig4(a1, hp, sv);
      u32x2 sp1 = {cvt_pk_bf16(sv[0], sv[1]), cvt_pk_bf16(sv[2], sv[3])};
      *(u32x2*)&h1L[(16 + lm) * 264 + row0] = hp;
      *(u32x2*)&s1L_[(16 + lm) * 264 + row0] = sp1;
    }
    __syncthreads();                               // B2: h1, s1 ready

    // ---- GEMM2: z2^T = W2 * h1^T (K=256), acc init = b2
    f32x4 c0 = bias2, c1 = bias2;
#pragma unroll
    for (int kt = 0; kt < 8; ++kt) {
      bf16x8 A = w2fG[(wv * 8 + kt) * 64 + lane];
      bf16x8 B0 = *(const bf16x8*)&h1L[lm * 264 + kt * 32 + ko8];
      bf16x8 B1 = *(const bf16x8*)&h1L[(16 + lm) * 264 + kt * 32 + ko8];
      c0 = MFMA16(A, B0, c0); c1 = MFMA16(A, B1, c1);
    }
    f32x4 s20, s21;
    {
      u32x2 hp;
      sp_sig4(c0, hp, s20);
      *(u32x2*)&h2L[lm * 264 + row0] = hp;
      sp_sig4(c1, hp, s21);
      *(u32x2*)&h2L[(16 + lm) * 264 + row0] = hp;
    }

    // ---- GEMMC: u^T = C * s1^T (K=256) — s1 ready since B2, overlap epi2
    f32x4 u0 = {0.f, 0.f, 0.f, 0.f}, u1 = {0.f, 0.f, 0.f, 0.f};
#pragma unroll
    for (int kt = 0; kt < 8; ++kt) {
      bf16x8 A = cfG[(wv * 8 + kt) * 64 + lane];
      bf16x8 B0 = *(const bf16x8*)&s1L_[lm * 264 + kt * 32 + ko8];
      bf16x8 B1 = *(const bf16x8*)&s1L_[(16 + lm) * 264 + kt * 32 + ko8];
      u0 = MFMA16(A, B0, u0); u1 = MFMA16(A, B1, u1);
    }
    float pl0 = u0[0] * s20[0] + u0[1] * s20[1] + u0[2] * s20[2] + u0[3] * s20[3];
    float pl1 = u1[0] * s21[0] + u1[1] * s21[1] + u1[2] * s21[2] + u1[3] * s21[3];
    pl0 += __shfl_xor(pl0, 16); pl0 += __shfl_xor(pl0, 32);
    pl1 += __shfl_xor(pl1, 16); pl1 += __shfl_xor(pl1, 32);
    if (lane < 16) { trPT[lm][wv] = pl0; trPT[16 + lm][wv] = pl1; }
    __syncthreads();                               // B3: h2 ready

    // ---- GEMM3: dy^T = W3 * h2^T (K=256, 2-way K-split), acc init = b3/0
    f32x4 d3a = bias3;
#pragma unroll
    for (int k = 0; k < 4; ++k) {
      int kt = kh * 4 + k;
      bf16x8 A = *(const bf16x8*)&w3f[((m3 * 8 + kt) * 64 + lane) * 8];
      bf16x8 B = *(const bf16x8*)&h2L[(c3 * 16 + lm) * 264 + kt * 32 + ko8];
      d3a = MFMA16(A, B, d3a);
    }
    *(f32x4*)&dyL[kh][c3 * 16 + lm][m3 * 16 + (lg << 2)] = d3a;
    __syncthreads();                               // B4: dy, trace ready

    f32x2 da = *(const f32x2*)&dyL[0][sl][q2 * 2];
    f32x2 db = *(const f32x2*)&dyL[1][sl][q2 * 2];
    dy = da + db;
    f32x4 t0 = *(const f32x4*)&trPT[sl][0];
    f32x4 t1 = *(const f32x4*)&trPT[sl][4];
    f32x4 t2 = *(const f32x4*)&trPT[sl][8];
    f32x4 t3 = *(const f32x4*)&trPT[sl][12];
    f32x4 ts = t0 + t1 + t2 + t3;
    tr = ts[0] + ts[1] + ts[2] + ts[3];
  };

  // Dormand-Prince 5(4), fixed 10 steps; dt premultiplied into coefficients
  const float A21 = dt * (1.f / 5.f);
  const float A31 = dt * (3.f / 40.f), A32 = dt * (9.f / 40.f);
  const float A41 = dt * (44.f / 45.f), A42 = dt * (-56.f / 15.f),
              A43 = dt * (32.f / 9.f);
  const float A51 = dt * (19372.f / 6561.f), A52 = dt * (-25360.f / 2187.f),
              A53 = dt * (64448.f / 6561.f), A54 = dt * (-212.f / 729.f);
  const float A61 = dt * (9017.f / 3168.f), A62 = dt * (-355.f / 33.f),
              A63 = dt * (46732.f / 5247.f), A64 = dt * (49.f / 176.f),
              A65 = dt * (-5103.f / 18656.f);
  const float C1 = dt * (35.f / 384.f), C3 = dt * (500.f / 1113.f),
              C4 = dt * (125.f / 192.f), C5 = dt * (-2187.f / 6784.f),
              C6 = dt * (11.f / 84.f);

  f32x2 k1, k2, k3, k4, k5, k6;
  float l1, l2, l3, l4, l5, l6;
#pragma unroll 1
  for (int step = 0; step < 10; ++step) {
    dyn(y, k1, l1);
    dyn(y + A21 * k1, k2, l2);
    dyn(y + A31 * k1 + A32 * k2, k3, l3);
    dyn(y + A41 * k1 + A42 * k2 + A43 * k3, k4, l4);
    dyn(y + A51 * k1 + A52 * k2 + A53 * k3 + A54 * k4, k5, l5);
    dyn(y + A61 * k1 + A62 * k2 + A63 * k3 + A64 * k4 + A65 * k5, k6, l6);
    y = y + C1 * k1 + C3 * k3 + C4 * k4 + C5 * k5 + C6 * k6;
    ld = ld + C1 * l1 + C3 * l3 + C4 * l4 + C5 * l5 + C6 * l6;
  }

  *(f32x2*)&outy[sg * 64 + q2 * 2] = y;
  if (q2 == 0) outl[sg] = ld;
}

extern "C" void kernel_launch(void* const* d_in, const int* in_sizes, int n_in,
                              void* d_out, int out_size, void* d_ws, size_t ws_size,
                              hipStream_t stream) {
  const float* x  = (const float*)d_in[0];
  const float* l0 = (const float*)d_in[1];
  const float* W1 = (const float*)d_in[2];
  const float* b1 = (const float*)d_in[3];
  const float* W2 = (const float*)d_in[4];
  const float* b2 = (const float*)d_in[5];
  const float* W3 = (const float*)d_in[6];
  const float* b3 = (const float*)d_in[7];
  const float* Tp = (const float*)d_in[8];
  short* ws = (short*)d_ws;

  cnf_prep<<<dim3(320), dim3(512), 0, stream>>>(W1, W2, W3, ws);

  float* outy = (float*)d_out;
  float* outl = outy + 8192 * 64;
  cnf_main<<<dim3(256), dim3(1024), 0, stream>>>(x, l0, b1, b2, b3, Tp, ws,
                                                 outy, outl);
}

// Round 6
// 525.241 us; speedup vs baseline: 1.0228x; 1.0217x over previous
//
#include <hip/hip_runtime.h>

typedef __attribute__((ext_vector_type(2))) float f32x2;
typedef __attribute__((ext_vector_type(4))) float f32x4;
typedef __attribute__((ext_vector_type(8))) short bf16x8;
typedef __attribute__((ext_vector_type(2))) unsigned u32x2;

#define MFMA16(a, b, c) __builtin_amdgcn_mfma_f32_16x16x32_bf16(a, b, c, 0, 0, 0)

// ws fragment offsets in shorts (bf16 elements)
#define W1F_OFF 0        // 16384 elems (M=256,K=64,  KT=2)
#define W2F_OFF 16384    // 65536 elems (M=256,K=256, KT=8)
#define CF_OFF  81920    // 65536 elems (M=256,K=256, KT=8)
#define W3F_OFF 147456   // 16384 elems (M=64, K=256, KT=8)

__device__ __forceinline__ short f2bf(float f) {
  unsigned u = __builtin_bit_cast(unsigned, f);
  u += 0x7FFFu + ((u >> 16) & 1u);          // RTNE (finite values only)
  return (short)(u >> 16);
}

__device__ __forceinline__ unsigned cvt_pk_bf16(float lo, float hi) {
  unsigned r;
  asm("v_cvt_pk_bf16_f32 %0, %1, %2" : "=v"(r) : "v"(lo), "v"(hi));
  return r;
}

__device__ __forceinline__ void sp_sig(float z, float& h, float& s) {
  // softplus + sigmoid sharing one exp: t = 2^(-|z|*log2e)
  float a = fabsf(z);
#if __has_builtin(__builtin_amdgcn_exp2f)
  float t = __builtin_amdgcn_exp2f(a * -1.44269504f);
#else
  float t = __expf(-a);
#endif
  float o = 1.f + t;
#if __has_builtin(__builtin_amdgcn_rcpf)
  float r = __builtin_amdgcn_rcpf(o);
#else
  float r = 1.f / o;
#endif
#if __has_builtin(__builtin_amdgcn_logf)
  float l2 = __builtin_amdgcn_logf(o);          // log2(o)
#else
  float l2 = __logf(o) * 1.44269504f;
#endif
  h = fmaxf(z, 0.f) + 0.69314718f * l2;
  s = (z >= 0.f) ? r : 1.f - r;
}

// softplus+sigmoid over an f32x4, packed outputs
__device__ __forceinline__ void sp_sig4(const f32x4& z, u32x2& hp, f32x4& sv) {
  float h0, h1, h2, h3, s0, s1, s2, s3;
  sp_sig(z[0], h0, s0); sp_sig(z[1], h1, s1);
  sp_sig(z[2], h2, s2); sp_sig(z[3], h3, s3);
  hp[0] = cvt_pk_bf16(h0, h1); hp[1] = cvt_pk_bf16(h2, h3);
  sv[0] = s0; sv[1] = s1; sv[2] = s2; sv[3] = s3;
}

// ---------------------------------------------------------------------------
// Prep: swizzle W1, W2, C = W2 .* (W1@W3)^T, W3 into MFMA A-fragment order.
// A[m][k] with m = mt*16 + (lane&15), k = kt*32 + (lane>>4)*8 + j
// ---------------------------------------------------------------------------
__global__ __launch_bounds__(512) void cnf_prep(const float* __restrict__ W1,
                                                const float* __restrict__ W2,
                                                const float* __restrict__ W3,
                                                short* __restrict__ ws) {
  int e = blockIdx.x * 512 + threadIdx.x;   // [0, 163840)
  int j = e & 7;
  int l = (e >> 3) & 63;
  int g = l >> 4, lm = l & 15;
  float val;
  if (e < 16384) {                          // W1 frag: [256 x 64]
    int t = e >> 9, kt = t & 1, mt = t >> 1;
    val = W1[(mt * 16 + lm) * 64 + kt * 32 + g * 8 + j];
  } else if (e < 81920) {                   // W2 frag: [256 x 256]
    int t = (e - 16384) >> 9, kt = t & 7, mt = t >> 3;
    val = W2[(mt * 16 + lm) * 256 + kt * 32 + g * 8 + j];
  } else if (e < 147456) {                  // C frag: C[m][k] = W2[m,k]*A2[k,m]
    int t = (e - 81920) >> 9, kt = t & 7, mt = t >> 3;
    int m = mt * 16 + lm, k = kt * 32 + g * 8 + j;
    float a2 = 0.f;
#pragma unroll 16
    for (int d = 0; d < 64; ++d) a2 += W1[k * 64 + d] * W3[d * 256 + m];
    val = W2[m * 256 + k] * a2;
  } else {                                  // W3 frag: [64 x 256]
    int t = (e - 147456) >> 9, kt = t & 7, mt = t >> 3;
    val = W3[(mt * 16 + lm) * 256 + kt * 32 + g * 8 + j];
  }
  ws[e] = f2bf(val);
}

// ---------------------------------------------------------------------------
// Main: 256 blocks x 1024 threads (16 waves, 1 block/CU via LDS).
// dyn is an always_inline lambda: in rounds 3-5 the inline-asm cvt_pk raised
// the inliner cost, dyn was outlined, and the by-reference out-params forced
// the ODE stage state (k1..k6,l1..l6) into scratch: 518MB FETCH + 351MB WRITE
// of spill traffic per dispatch. Forcing inline keeps everything in VGPRs.
// ---------------------------------------------------------------------------
__global__ __launch_bounds__(1024)
__attribute__((amdgpu_waves_per_eu(4, 4))) void cnf_main(
    const float* __restrict__ x, const float* __restrict__ ld_init,
    const float* __restrict__ b1g, const float* __restrict__ b2g,
    const float* __restrict__ b3g, const float* __restrict__ Tg,
    const short* __restrict__ ws, float* __restrict__ outy,
    float* __restrict__ outl) {
  __shared__ __align__(16) short w1f[16384];       // 32 KB persistent W1 frags
  __shared__ __align__(16) short w3f[16384];       // 32 KB persistent W3 frags
  __shared__ __align__(16) short ytL[32 * 88];     // stage input bf16 [s][d]
  __shared__ __align__(16) short h1L[32 * 264];    // softplus(z1) [col][row]
  __shared__ __align__(16) short s1L_[32 * 264];   // sigmoid(z1)
  __shared__ __align__(16) short h2L[32 * 264];    // softplus(z2)
  __shared__ __align__(16) float dyL[2][32][68];   // K-split partial dy
  __shared__ __align__(16) float trPT[32][16];     // trace partials [s][wv]

  const int tid = threadIdx.x;
  const int lane = tid & 63, wv = tid >> 6;        // 16 waves
  const int sl = tid >> 5, q2 = tid & 31;          // sample-local, dim-pair
  const int lg = lane >> 4, lm = lane & 15;
  const int ko8 = lg << 3;

  // Stage persistent weight fragments into LDS (2 x 16B per thread each)
  {
    const f32x4* s1p = (const f32x4*)(ws + W1F_OFF);
    f32x4* d1 = (f32x4*)w1f;
    d1[tid] = s1p[tid]; d1[tid + 1024] = s1p[tid + 1024];
    const f32x4* s3p = (const f32x4*)(ws + W3F_OFF);
    f32x4* d3 = (f32x4*)w3f;
    d3[tid] = s3p[tid]; d3[tid + 1024] = s3p[tid + 1024];
  }

  const int row0 = wv * 16 + (lg << 2);
  const f32x4 bias1 = *(const f32x4*)&b1g[row0];
  const f32x4 bias2 = *(const f32x4*)&b2g[row0];
  const int m3 = wv & 3, c3 = (wv >> 2) & 1, kh = wv >> 3;
  f32x4 bias3 = {0.f, 0.f, 0.f, 0.f};
  if (kh == 0) bias3 = *(const f32x4*)&b3g[m3 * 16 + (lg << 2)];

  const bf16x8* w2fG = (const bf16x8*)(ws + W2F_OFF);
  const bf16x8* cfG  = (const bf16x8*)(ws + CF_OFF);

  const int sg = blockIdx.x * 32 + sl;
  f32x2 y = *(const f32x2*)&x[sg * 64 + q2 * 2];
  float ld = ld_init[sg];
  const float dt = Tg[0] * 0.1f;                   // T / NUM_STEPS

  __syncthreads();

  auto dyn = [&](f32x2 yin, f32x2& dy, float& tr)
      __attribute__((always_inline)) {
    *(unsigned*)&ytL[sl * 88 + q2 * 2] = cvt_pk_bf16(yin[0], yin[1]);
    __syncthreads();                               // B1: ytmp ready

    // ---- GEMM1: z1^T = W1 * ytmp^T  (K=64), acc init = b1
    f32x4 a0 = bias1, a1 = bias1;
#pragma unroll
    for (int kt = 0; kt < 2; ++kt) {
      bf16x8 A = *(const bf16x8*)&w1f[((wv * 2 + kt) * 64 + lane) * 8];
      bf16x8 B0 = *(const bf16x8*)&ytL[lm * 88 + kt * 32 + ko8];
      bf16x8 B1 = *(const bf16x8*)&ytL[(16 + lm) * 88 + kt * 32 + ko8];
      a0 = MFMA16(A, B0, a0); a1 = MFMA16(A, B1, a1);
    }
    {
      u32x2 hp; f32x4 sv;
      sp_sig4(a0, hp, sv);
      u32x2 sp0 = {cvt_pk_bf16(sv[0], sv[1]), cvt_pk_bf16(sv[2], sv[3])};
      *(u32x2*)&h1L[lm * 264 + row0] = hp;
      *(u32x2*)&s1L_[lm * 264 + row0] = sp0;
      sp_sig4(a1, hp, sv);
      u32x2 sp1 = {cvt_pk_bf16(sv[0], sv[1]), cvt_pk_bf16(sv[2], sv[3])};
      *(u32x2*)&h1L[(16 + lm) * 264 + row0] = hp;
      *(u32x2*)&s1L_[(16 + lm) * 264 + row0] = sp1;
    }
    __syncthreads();                               // B2: h1, s1 ready

    // ---- GEMM2: z2^T = W2 * h1^T (K=256), acc init = b2
    f32x4 c0 = bias2, c1 = bias2;
#pragma unroll
    for (int kt = 0; kt < 8; ++kt) {
      bf16x8 A = w2fG[(wv * 8 + kt) * 64 + lane];
      bf16x8 B0 = *(const bf16x8*)&h1L[lm * 264 + kt * 32 + ko8];
      bf16x8 B1 = *(const bf16x8*)&h1L[(16 + lm) * 264 + kt * 32 + ko8];
      c0 = MFMA16(A, B0, c0); c1 = MFMA16(A, B1, c1);
    }
    f32x4 s20, s21;
    {
      u32x2 hp;
      sp_sig4(c0, hp, s20);
      *(u32x2*)&h2L[lm * 264 + row0] = hp;
      sp_sig4(c1, hp, s21);
      *(u32x2*)&h2L[(16 + lm) * 264 + row0] = hp;
    }

    // ---- GEMMC: u^T = C * s1^T (K=256) — s1 ready since B2, overlap epi2
    f32x4 u0 = {0.f, 0.f, 0.f, 0.f}, u1 = {0.f, 0.f, 0.f, 0.f};
#pragma unroll
    for (int kt = 0; kt < 8; ++kt) {
      bf16x8 A = cfG[(wv * 8 + kt) * 64 + lane];
      bf16x8 B0 = *(const bf16x8*)&s1L_[lm * 264 + kt * 32 + ko8];
      bf16x8 B1 = *(const bf16x8*)&s1L_[(16 + lm) * 264 + kt * 32 + ko8];
      u0 = MFMA16(A, B0, u0); u1 = MFMA16(A, B1, u1);
    }
    float pl0 = u0[0] * s20[0] + u0[1] * s20[1] + u0[2] * s20[2] + u0[3] * s20[3];
    float pl1 = u1[0] * s21[0] + u1[1] * s21[1] + u1[2] * s21[2] + u1[3] * s21[3];
    pl0 += __shfl_xor(pl0, 16); pl0 += __shfl_xor(pl0, 32);
    pl1 += __shfl_xor(pl1, 16); pl1 += __shfl_xor(pl1, 32);
    if (lane < 16) { trPT[lm][wv] = pl0; trPT[16 + lm][wv] = pl1; }
    __syncthreads();                               // B3: h2 ready

    // ---- GEMM3: dy^T = W3 * h2^T (K=256, 2-way K-split), acc init = b3/0
    f32x4 d3a = bias3;
#pragma unroll
    for (int k = 0; k < 4; ++k) {
      int kt = kh * 4 + k;
      bf16x8 A = *(const bf16x8*)&w3f[((m3 * 8 + kt) * 64 + lane) * 8];
      bf16x8 B = *(const bf16x8*)&h2L[(c3 * 16 + lm) * 264 + kt * 32 + ko8];
      d3a = MFMA16(A, B, d3a);
    }
    *(f32x4*)&dyL[kh][c3 * 16 + lm][m3 * 16 + (lg << 2)] = d3a;
    __syncthreads();                               // B4: dy, trace ready

    f32x2 da = *(const f32x2*)&dyL[0][sl][q2 * 2];
    f32x2 db = *(const f32x2*)&dyL[1][sl][q2 * 2];
    dy = da + db;
    f32x4 t0 = *(const f32x4*)&trPT[sl][0];
    f32x4 t1 = *(const f32x4*)&trPT[sl][4];
    f32x4 t2 = *(const f32x4*)&trPT[sl][8];
    f32x4 t3 = *(const f32x4*)&trPT[sl][12];
    f32x4 ts = t0 + t1 + t2 + t3;
    tr = ts[0] + ts[1] + ts[2] + ts[3];
  };

  // Dormand-Prince 5(4), fixed 10 steps; dt premultiplied into coefficients
  const float A21 = dt * (1.f / 5.f);
  const float A31 = dt * (3.f / 40.f), A32 = dt * (9.f / 40.f);
  const float A41 = dt * (44.f / 45.f), A42 = dt * (-56.f / 15.f),
              A43 = dt * (32.f / 9.f);
  const float A51 = dt * (19372.f / 6561.f), A52 = dt * (-25360.f / 2187.f),
              A53 = dt * (64448.f / 6561.f), A54 = dt * (-212.f / 729.f);
  const float A61 = dt * (9017.f / 3168.f), A62 = dt * (-355.f / 33.f),
              A63 = dt * (46732.f / 5247.f), A64 = dt * (49.f / 176.f),
              A65 = dt * (-5103.f / 18656.f);
  const float C1 = dt * (35.f / 384.f), C3 = dt * (500.f / 1113.f),
              C4 = dt * (125.f / 192.f), C5 = dt * (-2187.f / 6784.f),
              C6 = dt * (11.f / 84.f);

  f32x2 k1, k2, k3, k4, k5, k6;
  float tr;
#pragma unroll 1
  for (int step = 0; step < 10; ++step) {
    dyn(y, k1, tr);                                    ld += C1 * tr;
    dyn(y + A21 * k1, k2, tr);
    dyn(y + A31 * k1 + A32 * k2, k3, tr);              ld += C3 * tr;
    dyn(y + A41 * k1 + A42 * k2 + A43 * k3, k4, tr);   ld += C4 * tr;
    dyn(y + A51 * k1 + A52 * k2 + A53 * k3 + A54 * k4, k5, tr);
    ld += C5 * tr;
    dyn(y + A61 * k1 + A62 * k2 + A63 * k3 + A64 * k4 + A65 * k5, k6, tr);
    ld += C6 * tr;
    y = y + C1 * k1 + C3 * k3 + C4 * k4 + C5 * k5 + C6 * k6;
  }

  *(f32x2*)&outy[sg * 64 + q2 * 2] = y;
  if (q2 == 0) outl[sg] = ld;
}

extern "C" void kernel_launch(void* const* d_in, const int* in_sizes, int n_in,
                              void* d_out, int out_size, void* d_ws, size_t ws_size,
                              hipStream_t stream) {
  const float* x  = (const float*)d_in[0];
  const float* l0 = (const float*)d_in[1];
  const float* W1 = (const float*)d_in[2];
  const float* b1 = (const float*)d_in[3];
  const float* W2 = (const float*)d_in[4];
  const float* b2 = (const float*)d_in[5];
  const float* W3 = (const float*)d_in[6];
  const float* b3 = (const float*)d_in[7];
  const float* Tp = (const float*)d_in[8];
  short* ws = (short*)d_ws;

  cnf_prep<<<dim3(320), dim3(512), 0, stream>>>(W1, W2, W3, ws);

  float* outy = (float*)d_out;
  float* outl = outy + 8192 * 64;
  cnf_main<<<dim3(256), dim3(1024), 0, stream>>>(x, l0, b1, b2, b3, Tp, ws,
                                                 outy, outl);
}

// Round 7
// 380.665 us; speedup vs baseline: 1.4113x; 1.3798x over previous
//
#include <hip/hip_runtime.h>

typedef __attribute__((ext_vector_type(4))) float f32x4;
typedef __attribute__((ext_vector_type(8))) short bf16x8;
typedef __attribute__((ext_vector_type(4))) short bf16x4;

#define MFMA16(a, b, c) __builtin_amdgcn_mfma_f32_16x16x32_bf16(a, b, c, 0, 0, 0)

// ws fragment offsets in shorts (bf16 elements)
#define W1F_OFF 0        // 16384 elems (M=256,K=64,  KT=2)
#define W2F_OFF 16384    // 65536 elems (M=256,K=256, KT=8)
#define CF_OFF  81920    // 65536 elems (M=256,K=256, KT=8)
#define W3F_OFF 147456   // 16384 elems (M=64, K=256, KT=8)

// Native bf16 cast (RTNE). Backend pattern-matches adjacent pairs into
// v_cvt_pk_bf16_f32 (m240: do NOT hand-write the asm - breaks scheduling).
__device__ __forceinline__ short f2bf(float f) {
  __bf16 b = (__bf16)f;
  return __builtin_bit_cast(short, b);
}

__device__ __forceinline__ void sp_sig(float z, float& h, float& s) {
  // softplus + sigmoid sharing one exp: t = 2^(-|z|*log2e)
  float a = fabsf(z);
#if __has_builtin(__builtin_amdgcn_exp2f)
  float t = __builtin_amdgcn_exp2f(a * -1.44269504f);
#else
  float t = __expf(-a);
#endif
  float o = 1.f + t;
#if __has_builtin(__builtin_amdgcn_rcpf)
  float r = __builtin_amdgcn_rcpf(o);
#else
  float r = 1.f / o;
#endif
#if __has_builtin(__builtin_amdgcn_logf)
  float l2 = __builtin_amdgcn_logf(o);          // log2(o)
#else
  float l2 = __logf(o) * 1.44269504f;
#endif
  h = fmaxf(z, 0.f) + 0.69314718f * l2;
  s = (z >= 0.f) ? r : 1.f - r;
}

// ---------------------------------------------------------------------------
// Prep: swizzle W1, W2, C = W2 .* (W1@W3)^T, W3 into MFMA A-fragment order.
// A[m][k] with m = mt*16 + (lane&15), k = kt*32 + (lane>>4)*8 + j
// ---------------------------------------------------------------------------
__global__ __launch_bounds__(512) void cnf_prep(const float* __restrict__ W1,
                                                const float* __restrict__ W2,
                                                const float* __restrict__ W3,
                                                short* __restrict__ ws) {
  int e = blockIdx.x * 512 + threadIdx.x;   // [0, 163840)
  int j = e & 7;
  int l = (e >> 3) & 63;
  int g = l >> 4, lm = l & 15;
  float val;
  if (e < 16384) {                          // W1 frag: [256 x 64]
    int t = e >> 9, kt = t & 1, mt = t >> 1;
    val = W1[(mt * 16 + lm) * 64 + kt * 32 + g * 8 + j];
  } else if (e < 81920) {                   // W2 frag: [256 x 256]
    int t = (e - 16384) >> 9, kt = t & 7, mt = t >> 3;
    val = W2[(mt * 16 + lm) * 256 + kt * 32 + g * 8 + j];
  } else if (e < 147456) {                  // C frag: C[m][k] = W2[m,k]*A2[k,m]
    int t = (e - 81920) >> 9, kt = t & 7, mt = t >> 3;
    int m = mt * 16 + lm, k = kt * 32 + g * 8 + j;
    float a2 = 0.f;
#pragma unroll 16
    for (int d = 0; d < 64; ++d) a2 += W1[k * 64 + d] * W3[d * 256 + m];
    val = W2[m * 256 + k] * a2;
  } else {                                  // W3 frag: [64 x 256]
    int t = (e - 147456) >> 9, kt = t & 7, mt = t >> 3;
    val = W3[(mt * 16 + lm) * 256 + kt * 32 + g * 8 + j];
  }
  ws[e] = f2bf(val);
}

// ---------------------------------------------------------------------------
// Main: 256 blocks x 512 threads (8 waves, proven spill-free shape: wg=1024
// forces a 128-total-reg budget -> 870MB scratch traffic; wg=512 runs at
// 2 waves/SIMD with a 256-reg budget). Block b integrates samples
// [32b,32b+32) through 10 Dopri5 steps; 4 bf16 MFMA GEMMs per dyn().
// Biases folded into MFMA acc init; native bf16 casts; exp2/log2/rcp.
// ---------------------------------------------------------------------------
__global__ __launch_bounds__(512) void cnf_main(
    const float* __restrict__ x, const float* __restrict__ ld_init,
    const float* __restrict__ b1g, const float* __restrict__ b2g,
    const float* __restrict__ b3g, const float* __restrict__ Tg,
    const short* __restrict__ ws, float* __restrict__ outy,
    float* __restrict__ outl) {
  __shared__ __align__(16) short w1f[16384];       // 32 KB persistent W1 frags
  __shared__ __align__(16) short w3f[16384];       // 32 KB persistent W3 frags
  __shared__ __align__(16) short ytL[32 * 88];     // stage input, bf16 [s][d]
  __shared__ __align__(16) short h1L[32 * 264];    // softplus(z1), [col][row]
  __shared__ __align__(16) short s1L_[32 * 264];   // sigmoid(z1)
  __shared__ __align__(16) short h2L[32 * 264];    // softplus(z2)
  __shared__ __align__(16) float dyL[32 * 68];     // dy f32 [s][d], stride 68
  __shared__ __align__(16) float trPT[32][12];     // trace partials [s][wv]

  const int tid = threadIdx.x;
  const int lane = tid & 63, wv = tid >> 6;        // 8 waves
  const int sl = tid >> 4, q = tid & 15;           // sample-local, d-chunk
  const int lg = lane >> 4, lm = lane & 15;
  const int ko8 = lg << 3;

  // Stage persistent weight fragments into LDS
  {
    const f32x4* s1p = (const f32x4*)(ws + W1F_OFF);
    f32x4* d1 = (f32x4*)w1f;
#pragma unroll
    for (int i = 0; i < 4; ++i) d1[tid + 512 * i] = s1p[tid + 512 * i];
    const f32x4* s3p = (const f32x4*)(ws + W3F_OFF);
    f32x4* d3 = (f32x4*)w3f;
#pragma unroll
    for (int i = 0; i < 4; ++i) d3[tid + 512 * i] = s3p[tid + 512 * i];
  }

  // Per-thread bias fragments (folded into MFMA acc init)
  const int row0a = (2 * wv + 0) * 16 + (lg << 2);
  const int row0b = (2 * wv + 1) * 16 + (lg << 2);
  const f32x4 bias1a = *(const f32x4*)&b1g[row0a];
  const f32x4 bias1b = *(const f32x4*)&b1g[row0b];
  const f32x4 bias2a = *(const f32x4*)&b2g[row0a];
  const f32x4 bias2b = *(const f32x4*)&b2g[row0b];
  const int m3 = wv & 3, c3 = wv >> 2;
  const f32x4 bias3 = *(const f32x4*)&b3g[m3 * 16 + (lg << 2)];

  const bf16x8* w2fG = (const bf16x8*)(ws + W2F_OFF);
  const bf16x8* cfG  = (const bf16x8*)(ws + CF_OFF);

  const int sg = blockIdx.x * 32 + sl;
  f32x4 y = *(const f32x4*)&x[sg * 64 + q * 4];
  float ld = ld_init[sg];
  const float dt = Tg[0] * 0.1f;                   // T / NUM_STEPS

  __syncthreads();

  auto dyn = [&](f32x4 yin, f32x4& dy, float& tr)
      __attribute__((always_inline)) {
    // stage input -> LDS (bf16)
    bf16x4 yb;
#pragma unroll
    for (int r = 0; r < 4; ++r) yb[r] = f2bf(yin[r]);
    *(bf16x4*)&ytL[sl * 88 + q * 4] = yb;
    __syncthreads();                               // B1: ytmp ready

    // ---- GEMM1: z1^T = W1 * ytmp^T  (K=64), acc init = b1
    f32x4 a00 = bias1a, a01 = bias1a, a10 = bias1b, a11 = bias1b;
#pragma unroll
    for (int kt = 0; kt < 2; ++kt) {
      bf16x8 A0 = *(const bf16x8*)&w1f[(((2 * wv + 0) * 2 + kt) * 64 + lane) * 8];
      bf16x8 A1 = *(const bf16x8*)&w1f[(((2 * wv + 1) * 2 + kt) * 64 + lane) * 8];
      bf16x8 B0 = *(const bf16x8*)&ytL[lm * 88 + kt * 32 + ko8];
      bf16x8 B1 = *(const bf16x8*)&ytL[(16 + lm) * 88 + kt * 32 + ko8];
      a00 = MFMA16(A0, B0, a00); a01 = MFMA16(A0, B1, a01);
      a10 = MFMA16(A1, B0, a10); a11 = MFMA16(A1, B1, a11);
    }
    {
      auto epi1 = [&](const f32x4& z4, int r0, int c)
          __attribute__((always_inline)) {
        int sc = c * 16 + lm;
        bf16x4 hh, ss;
#pragma unroll
        for (int r = 0; r < 4; ++r) {
          float h, s;
          sp_sig(z4[r], h, s);
          hh[r] = f2bf(h); ss[r] = f2bf(s);
        }
        *(bf16x4*)&h1L[sc * 264 + r0] = hh;
        *(bf16x4*)&s1L_[sc * 264 + r0] = ss;
      };
      epi1(a00, row0a, 0); epi1(a01, row0a, 1);
      epi1(a10, row0b, 0); epi1(a11, row0b, 1);
    }
    __syncthreads();                               // B2: h1, s1 ready

    // ---- GEMM2: z2^T = W2 * h1^T (K=256), acc init = b2
    f32x4 c00 = bias2a, c01 = bias2a, c10 = bias2b, c11 = bias2b;
#pragma unroll
    for (int kt = 0; kt < 8; ++kt) {
      bf16x8 A0 = w2fG[((2 * wv + 0) * 8 + kt) * 64 + lane];
      bf16x8 A1 = w2fG[((2 * wv + 1) * 8 + kt) * 64 + lane];
      bf16x8 B0 = *(const bf16x8*)&h1L[lm * 264 + kt * 32 + ko8];
      bf16x8 B1 = *(const bf16x8*)&h1L[(16 + lm) * 264 + kt * 32 + ko8];
      c00 = MFMA16(A0, B0, c00); c01 = MFMA16(A0, B1, c01);
      c10 = MFMA16(A1, B0, c10); c11 = MFMA16(A1, B1, c11);
    }
    f32x4 s200, s201, s210, s211;
    {
      auto epi2 = [&](const f32x4& z4, int r0, int c, f32x4& s2o)
          __attribute__((always_inline)) {
        int sc = c * 16 + lm;
        bf16x4 hh;
#pragma unroll
        for (int r = 0; r < 4; ++r) {
          float h, s;
          sp_sig(z4[r], h, s);
          hh[r] = f2bf(h); s2o[r] = s;
        }
        *(bf16x4*)&h2L[sc * 264 + r0] = hh;
      };
      epi2(c00, row0a, 0, s200); epi2(c01, row0a, 1, s201);
      epi2(c10, row0b, 0, s210); epi2(c11, row0b, 1, s211);
    }

    // ---- GEMMC: u^T = C * s1^T (K=256) — s1 ready since B2, overlaps epi2
    f32x4 u00 = {0,0,0,0}, u01 = {0,0,0,0}, u10 = {0,0,0,0}, u11 = {0,0,0,0};
#pragma unroll
    for (int kt = 0; kt < 8; ++kt) {
      bf16x8 A0 = cfG[((2 * wv + 0) * 8 + kt) * 64 + lane];
      bf16x8 A1 = cfG[((2 * wv + 1) * 8 + kt) * 64 + lane];
      bf16x8 B0 = *(const bf16x8*)&s1L_[lm * 264 + kt * 32 + ko8];
      bf16x8 B1 = *(const bf16x8*)&s1L_[(16 + lm) * 264 + kt * 32 + ko8];
      u00 = MFMA16(A0, B0, u00); u01 = MFMA16(A0, B1, u01);
      u10 = MFMA16(A1, B0, u10); u11 = MFMA16(A1, B1, u11);
    }
    float pl0 = 0.f, pl1 = 0.f;
#pragma unroll
    for (int r = 0; r < 4; ++r) {
      pl0 += u00[r] * s200[r] + u10[r] * s210[r];
      pl1 += u01[r] * s201[r] + u11[r] * s211[r];
    }
    pl0 += __shfl_xor(pl0, 16); pl0 += __shfl_xor(pl0, 32);
    pl1 += __shfl_xor(pl1, 16); pl1 += __shfl_xor(pl1, 32);
    if (lane < 16) { trPT[lane][wv] = pl0; trPT[16 + lane][wv] = pl1; }

    // ---- GEMM3: dy^T = W3 * h2^T (K=256), one 16x16 tile per wave
    f32x4 d3a = bias3;
#pragma unroll
    for (int kt = 0; kt < 8; ++kt) {
      bf16x8 A0 = *(const bf16x8*)&w3f[((m3 * 8 + kt) * 64 + lane) * 8];
      bf16x8 B0 = *(const bf16x8*)&h2L[(c3 * 16 + lm) * 264 + kt * 32 + ko8];
      d3a = MFMA16(A0, B0, d3a);
    }
    *(f32x4*)&dyL[(c3 * 16 + lm) * 68 + m3 * 16 + (lg << 2)] = d3a;
    __syncthreads();                               // B4: dy, trace ready

    dy = *(const f32x4*)&dyL[sl * 68 + q * 4];
    f32x4 t0 = *(const f32x4*)&trPT[sl][0];
    f32x4 t1 = *(const f32x4*)&trPT[sl][4];
    f32x4 ts = t0 + t1;
    tr = ts[0] + ts[1] + ts[2] + ts[3];
  };

  // Dormand-Prince 5(4), fixed 10 steps; dt premultiplied into coefficients
  const float A21 = dt * (1.f / 5.f);
  const float A31 = dt * (3.f / 40.f), A32 = dt * (9.f / 40.f);
  const float A41 = dt * (44.f / 45.f), A42 = dt * (-56.f / 15.f),
              A43 = dt * (32.f / 9.f);
  const float A51 = dt * (19372.f / 6561.f), A52 = dt * (-25360.f / 2187.f),
              A53 = dt * (64448.f / 6561.f), A54 = dt * (-212.f / 729.f);
  const float A61 = dt * (9017.f / 3168.f), A62 = dt * (-355.f / 33.f),
              A63 = dt * (46732.f / 5247.f), A64 = dt * (49.f / 176.f),
              A65 = dt * (-5103.f / 18656.f);
  const float C1 = dt * (35.f / 384.f), C3 = dt * (500.f / 1113.f),
              C4 = dt * (125.f / 192.f), C5 = dt * (-2187.f / 6784.f),
              C6 = dt * (11.f / 84.f);

  f32x4 k1, k2, k3, k4, k5, k6;
  float tr;
#pragma unroll 1
  for (int step = 0; step < 10; ++step) {
    dyn(y, k1, tr);                                          ld += C1 * tr;
    dyn(y + A21 * k1, k2, tr);
    dyn(y + A31 * k1 + A32 * k2, k3, tr);                    ld += C3 * tr;
    dyn(y + A41 * k1 + A42 * k2 + A43 * k3, k4, tr);         ld += C4 * tr;
    dyn(y + A51 * k1 + A52 * k2 + A53 * k3 + A54 * k4, k5, tr);
    ld += C5 * tr;
    dyn(y + A61 * k1 + A62 * k2 + A63 * k3 + A64 * k4 + A65 * k5, k6, tr);
    ld += C6 * tr;
    y = y + C1 * k1 + C3 * k3 + C4 * k4 + C5 * k5 + C6 * k6;
  }

  *(f32x4*)&outy[sg * 64 + q * 4] = y;
  if (q == 0) outl[sg] = ld;
}

extern "C" void kernel_launch(void* const* d_in, const int* in_sizes, int n_in,
                              void* d_out, int out_size, void* d_ws, size_t ws_size,
                              hipStream_t stream) {
  const float* x  = (const float*)d_in[0];
  const float* l0 = (const float*)d_in[1];
  const float* W1 = (const float*)d_in[2];
  const float* b1 = (const float*)d_in[3];
  const float* W2 = (const float*)d_in[4];
  const float* b2 = (const float*)d_in[5];
  const float* W3 = (const float*)d_in[6];
  const float* b3 = (const float*)d_in[7];
  const float* Tp = (const float*)d_in[8];
  short* ws = (short*)d_ws;

  cnf_prep<<<dim3(320), dim3(512), 0, stream>>>(W1, W2, W3, ws);

  float* outy = (float*)d_out;
  float* outl = outy + 8192 * 64;
  cnf_main<<<dim3(256), dim3(512), 0, stream>>>(x, l0, b1, b2, b3, Tp, ws,
                                                outy, outl);
}